// Round 10
// baseline (312.726 us; speedup 1.0000x reference)
//
#include <hip/hip_runtime.h>
#include <math.h>

#define BB 32
#define NN 96
#define DD 32
#define FF 16
#define NE (NN * NN)          // 9216 edges per batch
#define PAIRS (BB * NN)       // 3072 (b,i) pairs
#define PPB 12                // pairs per block
#define GRID_F (PAIRS / PPB)  // 256 blocks = exactly 1 per CU
#define EG 6                  // edges per inner group
#define MAXG (PPB * 16)       // max groups per block (ceil(96/6)=16 per pair)

// ---------------------------------------------------------------------------
// Fused kernel, round-7 structure: ALL edge features LDS-resident.
//   1024-thread block owns 12 pairs; masked edge rows are reg-staged
//   (issue-early/write-late) into a 73.7KB LDS buffer ONCE, then the compute
//   loop is pure LDS+VALU. Flat group queue over all 12 pairs balances the
//   16 waves (wave w: set s=w>>2 takes groups s, s+4, ...; tq=w&3 is k-chunk).
//   Lane l owns k = 256tq + 4l + c (c=0..3): p-dim = 8tq + (l>>3) (one reg),
//   q = 4(l&7)+c. Per-group partial reduced over l8 (3 shfl) then ONE LDS
//   atomicAdd per 8 lanes -> no runtime-indexed reg arrays (rule #20).
//
// Round-9 change: __launch_bounds__(1024, 2). Round 8 ran this exact kernel
// with no occupancy arg -> compiler targeted 8 waves/SIMD -> VGPR cap 64 ->
// ~1GB scratch spill traffic (WRITE 686MB), VALUBusy 22%, 243us. A
// 1024-thread block needs 4 waves/SIMD resident; empirical cap model
// (cap = 256/arg2: (256,2)->128, (512,4)->64) gives (1024,2)->128, which is
// both the HW max for a 1024-thr block (4 waves/SIMD x 128 = 512 pool) and
// what the ~115-float live set needs; rounds 4-6 proved this inner loop
// fits 128 with zero spill.
// Mask==0 edges skipped exactly (mask is exactly 0.0/1.0).
// LDS ~158KB (1 block/CU by design).
// ---------------------------------------------------------------------------
__device__ __forceinline__ float dot32(const float* __restrict__ x,
                                       const float* __restrict__ w) {
    float s = 0.f;
    #pragma unroll
    for (int u = 0; u < 8; ++u) {
        float4 a = *(const float4*)(x + 4 * u);
        float4 c = *(const float4*)(w + 4 * u);
        s = fmaf(a.x, c.x, fmaf(a.y, c.y, fmaf(a.z, c.z, fmaf(a.w, c.w, s))));
    }
    return s;
}
__device__ __forceinline__ float sigm(float x) { return 1.f / (1.f + expf(-x)); }

__global__ __launch_bounds__(1024, 2)
void mp_fused(const float* __restrict__ nodes, const float* __restrict__ edges,
              const float* __restrict__ mask, const float* __restrict__ W_agg,
              const float* __restrict__ b_agg,
              const float* __restrict__ w_ih, const float* __restrict__ w_hh,
              const float* __restrict__ b_ih, const float* __restrict__ b_hh,
              float* __restrict__ out) {
    __shared__ __align__(16) float Wl[FF * 1024];     // 64 KB; reused for GRU
    __shared__ __align__(16) float nodl[NN * DD];     // 12 KB
    __shared__ float4 ebufq[PPB * 384];               // 73.7 KB edge features
    __shared__ int   jlf[PPB * NN];                   // 4.6 KB compacted j
    __shared__ int   jcnt[PPB];
    __shared__ int   g2p[MAXG];
    __shared__ int   g2e0[MAXG];
    __shared__ int   gtot_s;
    __shared__ float aggv[PPB][DD];
    __shared__ float h1v[PPB][DD];
    __shared__ float bih_s[96], bhh_s[96];

    const int tid  = threadIdx.x;
    const int lane = tid & 63;
    const int wv   = tid >> 6;       // 0..15
    const int tq   = wv & 3;         // k-chunk
    const int s    = wv >> 2;        // group-queue set (stride 4)
    const int pair0 = blockIdx.x * PPB;
    const int b  = pair0 / NN;
    const int i0 = pair0 % NN;
    const int l8 = lane & 7;         // q-chunk id
    const int lp = lane >> 3;        // p offset within k-chunk
    const int wbase = 256 * tq + 4 * lane;

    // ---- prologue: zero counters, stage W + nodes ----
    if (tid < PPB) jcnt[tid] = 0;
    if (tid < PPB * DD) ((float*)aggv)[tid] = 0.f;
    #pragma unroll
    for (int c = 0; c < 4; ++c)
        ((float4*)Wl)[c * 1024 + tid] = ((const float4*)W_agg)[c * 1024 + tid];
    if (tid < 768)
        ((float4*)nodl)[tid] = ((const float4*)(nodes + b * NN * DD))[tid];
    const float4 bvv = *(const float4*)(b_agg + wbase);
    __syncthreads();                                  // A: jcnt zeroed

    // ---- compact all 12 pairs' unmasked edges (order irrelevant to sum) ----
    for (int v = tid; v < PPB * NN; v += 1024) {
        const int p = v / NN, col = v % NN;
        if (mask[(size_t)b * NE + (size_t)(i0 + p) * NN + col] != 0.f) {
            int pos = atomicAdd(&jcnt[p], 1);
            jlf[p * NN + pos] = col;
        }
    }
    __syncthreads();                                  // B: jlf/jcnt final

    // ---- build flat group map (12 threads) ----
    if (tid < PPB) {
        int gs = 0;
        for (int q = 0; q < PPB; ++q)
            if (q < tid) gs += (jcnt[q] + EG - 1) / EG;
        const int gp = (jcnt[tid] + EG - 1) / EG;
        for (int g = 0; g < gp; ++g) { g2p[gs + g] = tid; g2e0[gs + g] = g * EG; }
        if (tid == PPB - 1) gtot_s = gs + gp;
    }
    // ---- reg-stage masked edge rows: issue all loads, then write to LDS ----
    {
        float4 sv[5];
        bool   sa[5];
        #pragma unroll
        for (int k = 0; k < 5; ++k) {
            const int t = tid + k * 1024;
            bool act = (t < PPB * 384);
            int p = 0, e = 0, ch = 0;
            if (act) {
                p = t / 384; const int lt = t - p * 384;
                e = lt >> 2; ch = lt & 3;
                act = (e < jcnt[p]);
            }
            sa[k] = act;
            if (act) {
                const int row = jlf[p * NN + e];
                sv[k] = *(const float4*)(edges +
                    ((size_t)b * NE + (size_t)(i0 + p) * NN + row) * FF + ch * 4);
            }
        }
        #pragma unroll
        for (int k = 0; k < 5; ++k)
            if (sa[k]) ebufq[tid + k * 1024] = sv[k];
    }
    __syncthreads();                                  // C: ebuf + gmap ready

    // ---- compute: pure LDS+VALU group loop ----
    const float4* Wlq   = (const float4*)Wl;
    const float4* nodlq = (const float4*)nodl;
    const int Gtot = gtot_s;
    const int wq4  = 64 * tq + lane;                  // W float4 idx per f-row
    for (int fg = s; fg < Gtot; fg += 4) {
        const int p   = __builtin_amdgcn_readfirstlane(g2p[fg]);
        const int e0g = __builtin_amdgcn_readfirstlane(g2e0[fg]);
        const int cnt = __builtin_amdgcn_readfirstlane(jcnt[p]);
        const int ecnt = cnt - e0g;                   // >=1; epilogue caps at EG
        int jj[EG];
        #pragma unroll
        for (int e = 0; e < EG; ++e) {
            int idx = e0g + e; if (idx > cnt - 1) idx = cnt - 1;
            jj[e] = __builtin_amdgcn_readfirstlane(jlf[p * NN + idx]);
        }
        float acc[EG][4];
        #pragma unroll
        for (int e = 0; e < EG; ++e) {
            acc[e][0] = bvv.x; acc[e][1] = bvv.y;
            acc[e][2] = bvv.z; acc[e][3] = bvv.w;
        }
        const float4* fb = ebufq + p * 384 + e0g * 4; // uniform -> broadcast
        #pragma unroll
        for (int u = 0; u < 4; ++u) {
            float4 ev[EG];
            #pragma unroll
            for (int e = 0; e < EG; ++e) ev[e] = fb[e * 4 + u];
            #pragma unroll
            for (int f2 = 0; f2 < 4; ++f2) {
                const float4 w4 = Wlq[(4 * u + f2) * 256 + wq4];
                #pragma unroll
                for (int e = 0; e < EG; ++e) {
                    const float ef = (f2 == 0) ? ev[e].x : (f2 == 1) ? ev[e].y
                                   : (f2 == 2) ? ev[e].z : ev[e].w;
                    acc[e][0] = fmaf(ef, w4.x, acc[e][0]);
                    acc[e][1] = fmaf(ef, w4.y, acc[e][1]);
                    acc[e][2] = fmaf(ef, w4.z, acc[e][2]);
                    acc[e][3] = fmaf(ef, w4.w, acc[e][3]);
                }
            }
        }
        // epilogue: relu * nodes[j][q-chunk]; per-group partial in one reg
        float r = 0.f;
        #pragma unroll
        for (int e = 0; e < EG; ++e) {
            if (e < ecnt) {
                const float4 x4 = nodlq[jj[e] * 8 + l8];
                r = fmaf(fmaxf(acc[e][0], 0.f), x4.x, r);
                r = fmaf(fmaxf(acc[e][1], 0.f), x4.y, r);
                r = fmaf(fmaxf(acc[e][2], 0.f), x4.z, r);
                r = fmaf(fmaxf(acc[e][3], 0.f), x4.w, r);
            }
        }
        r += __shfl_xor(r, 1, 64);
        r += __shfl_xor(r, 2, 64);
        r += __shfl_xor(r, 4, 64);
        if (l8 == 0) atomicAdd(&aggv[p][8 * tq + lp], r);
    }
    __syncthreads();                                  // D: aggv final

    // ---- GRU phase: reuse Wl for w_ih/w_hh (padded stride 36) ----
    float* wihL = Wl;                // 96*36 floats
    float* whhL = Wl + 3456;
    if (tid < 768) {
        const int row = tid >> 3, c4 = tid & 7;
        *(float4*)&wihL[row * 36 + c4 * 4] = ((const float4*)w_ih)[tid];
        *(float4*)&whhL[row * 36 + c4 * 4] = ((const float4*)w_hh)[tid];
    }
    if (tid < 96) { bih_s[tid] = b_ih[tid]; bhh_s[tid] = b_hh[tid]; }
    __syncthreads();                                  // E: GRU weights ready

    if (tid < PPB * DD) {
        const int pp = tid >> 5, d = tid & 31;
        const float* x = nodl + (i0 + pp) * DD;
        // cell 1: h = 0 -> gh = b_hh exactly
        float gi_r = dot32(x, &wihL[(0 * 32 + d) * 36]) + bih_s[d];
        float gi_z = dot32(x, &wihL[(1 * 32 + d) * 36]) + bih_s[32 + d];
        float gi_n = dot32(x, &wihL[(2 * 32 + d) * 36]) + bih_s[64 + d];
        float r1 = sigm(gi_r + bhh_s[d]);
        float z1 = sigm(gi_z + bhh_s[32 + d]);
        float n1 = tanhf(gi_n + r1 * bhh_s[64 + d]);
        h1v[pp][d] = (1.f - z1) * n1;
    }
    __syncthreads();                                  // F: h1 ready
    if (tid < PPB * DD) {
        const int pp = tid >> 5, d = tid & 31;
        const float* a  = &aggv[pp][0];
        const float* h1 = &h1v[pp][0];
        float gi_r = dot32(a, &wihL[(0 * 32 + d) * 36]) + bih_s[d];
        float gi_z = dot32(a, &wihL[(1 * 32 + d) * 36]) + bih_s[32 + d];
        float gi_n = dot32(a, &wihL[(2 * 32 + d) * 36]) + bih_s[64 + d];
        float gh_r = dot32(h1, &whhL[(0 * 32 + d) * 36]) + bhh_s[d];
        float gh_z = dot32(h1, &whhL[(1 * 32 + d) * 36]) + bhh_s[32 + d];
        float gh_n = dot32(h1, &whhL[(2 * 32 + d) * 36]) + bhh_s[64 + d];
        float r2 = sigm(gi_r + gh_r);
        float z2 = sigm(gi_z + gh_z);
        float n2 = tanhf(gi_n + r2 * gh_n);
        float h2 = (1.f - z2) * n2 + z2 * h1[d];
        out[(size_t)(pair0 + pp) * DD + d] = h2;
    }
}

extern "C" void kernel_launch(void* const* d_in, const int* in_sizes, int n_in,
                              void* d_out, int out_size, void* d_ws, size_t ws_size,
                              hipStream_t stream) {
    const float* nodes = (const float*)d_in[0];
    const float* edges = (const float*)d_in[1];
    const float* mask  = (const float*)d_in[2];
    const float* W_agg = (const float*)d_in[3];
    const float* b_agg = (const float*)d_in[4];
    const float* w_ih  = (const float*)d_in[5];
    const float* w_hh  = (const float*)d_in[6];
    const float* b_ih  = (const float*)d_in[7];
    const float* b_hh  = (const float*)d_in[8];
    float* out = (float*)d_out;

    mp_fused<<<GRID_F, 1024, 0, stream>>>(nodes, edges, mask, W_agg, b_agg,
                                          w_ih, w_hh, b_ih, b_hh, out);
}

// Round 15
// 144.714 us; speedup vs baseline: 2.1610x; 2.1610x over previous
//
#include <hip/hip_runtime.h>
#include <math.h>

#define BB 32
#define NN 96
#define DD 32
#define FF 16
#define NE (NN * NN)          // 9216 edges per batch
#define PAIRS (BB * NN)       // 3072 (b,i) pairs
#define PPB 12                // pairs per block
#define GRID_F (PAIRS / PPB)  // 256 blocks = exactly 1 per CU
#define EG 6                  // edges per inner group
#define MAXG (PPB * 16)       // max groups per block (ceil(96/6)=16 per pair)

// ---------------------------------------------------------------------------
// Fused kernel: ALL edge features LDS-resident (r7 structure) at 512 threads.
//
// VGPR-cap model (5 empirical points: (256,2)->128, (512,2)->128, (512,4)->64,
// (1024,none)->64, (1024,2)->64):  cap = 256 / max(arg2, waves_per_block/4).
// A 1024-thr block (4 waves/SIMD resident minimum) is hard-capped at 64 ->
// r8/r10's ~1GB spill traffic regardless of launch bounds. 512-thr + arg2=2
// gives cap 128, proven spill-free with this exact inner loop in r4-6.
//
// Structure: 512-thr block owns 12 pairs; masked edge rows reg-staged
// (issue-all-then-write) into 73.7KB LDS ONCE; compute loop is pure LDS+VALU.
// Flat group queue over 12 pairs balances 8 waves: wave w: set s=w>>2 (stride
// 2), k-chunk tq=w&3. Lane l owns k = 256tq + 4l + c (c=0..3):
//   p-dim = 8tq + (l>>3) (constant per lane -> one aggregate register)
//   q     = 4(l&7) + c   (float4 of nodes[j], 8-way broadcast read)
// W read per f: ds_read_b128 at Wl[f*1024 + 256tq + 4l], conflict-free.
// Per-group partial reduced over l8 (3 shfl) then ONE LDS atomicAdd per 8
// lanes -> no runtime-indexed register arrays (rule #20).
// Mask==0 edges skipped exactly (mask is exactly 0.0/1.0).
// LDS ~158KB -> 1 block/CU; 8 waves = 2 waves/SIMD; 24-way FMA ILP per
// dep chain keeps the VALU pipe fed at that occupancy.
// ---------------------------------------------------------------------------
__device__ __forceinline__ float dot32(const float* __restrict__ x,
                                       const float* __restrict__ w) {
    float s = 0.f;
    #pragma unroll
    for (int u = 0; u < 8; ++u) {
        float4 a = *(const float4*)(x + 4 * u);
        float4 c = *(const float4*)(w + 4 * u);
        s = fmaf(a.x, c.x, fmaf(a.y, c.y, fmaf(a.z, c.z, fmaf(a.w, c.w, s))));
    }
    return s;
}
__device__ __forceinline__ float sigm(float x) { return 1.f / (1.f + expf(-x)); }

__global__ __launch_bounds__(512, 2)
void mp_fused(const float* __restrict__ nodes, const float* __restrict__ edges,
              const float* __restrict__ mask, const float* __restrict__ W_agg,
              const float* __restrict__ b_agg,
              const float* __restrict__ w_ih, const float* __restrict__ w_hh,
              const float* __restrict__ b_ih, const float* __restrict__ b_hh,
              float* __restrict__ out) {
    __shared__ __align__(16) float Wl[FF * 1024];     // 64 KB; reused for GRU
    __shared__ __align__(16) float nodl[NN * DD];     // 12 KB
    __shared__ float4 ebufq[PPB * 384];               // 73.7 KB edge features
    __shared__ int   jlf[PPB * NN];                   // 4.6 KB compacted j
    __shared__ int   jcnt[PPB];
    __shared__ int   g2p[MAXG];
    __shared__ int   g2e0[MAXG];
    __shared__ int   gtot_s;
    __shared__ float aggv[PPB][DD];
    __shared__ float h1v[PPB][DD];
    __shared__ float bih_s[96], bhh_s[96];

    const int tid  = threadIdx.x;
    const int lane = tid & 63;
    const int wv   = tid >> 6;       // 0..7
    const int tq   = wv & 3;         // k-chunk
    const int s    = wv >> 2;        // group-queue set (stride 2)
    const int pair0 = blockIdx.x * PPB;
    const int b  = pair0 / NN;
    const int i0 = pair0 % NN;
    const int l8 = lane & 7;         // q-chunk id
    const int lp = lane >> 3;        // p offset within k-chunk
    const int wbase = 256 * tq + 4 * lane;

    // ---- prologue: zero counters, stage W + nodes ----
    if (tid < PPB) jcnt[tid] = 0;
    if (tid < PPB * DD) ((float*)aggv)[tid] = 0.f;
    #pragma unroll
    for (int c = 0; c < 8; ++c)
        ((float4*)Wl)[c * 512 + tid] = ((const float4*)W_agg)[c * 512 + tid];
    for (int v = tid; v < 768; v += 512)
        ((float4*)nodl)[v] = ((const float4*)(nodes + b * NN * DD))[v];
    const float4 bvv = *(const float4*)(b_agg + wbase);
    __syncthreads();                                  // A: jcnt zeroed

    // ---- compact all 12 pairs' unmasked edges (order irrelevant to sum) ----
    for (int v = tid; v < PPB * NN; v += 512) {
        const int p = v / NN, col = v % NN;
        if (mask[(size_t)b * NE + (size_t)(i0 + p) * NN + col] != 0.f) {
            int pos = atomicAdd(&jcnt[p], 1);
            jlf[p * NN + pos] = col;
        }
    }
    __syncthreads();                                  // B: jlf/jcnt final

    // ---- build flat group map (12 threads) ----
    if (tid < PPB) {
        int gs = 0;
        for (int q = 0; q < PPB; ++q)
            if (q < tid) gs += (jcnt[q] + EG - 1) / EG;
        const int gp = (jcnt[tid] + EG - 1) / EG;
        for (int g = 0; g < gp; ++g) { g2p[gs + g] = tid; g2e0[gs + g] = g * EG; }
        if (tid == PPB - 1) gtot_s = gs + gp;
    }
    // ---- reg-stage masked edge rows: issue all loads, then write to LDS ----
    {
        float4 sv[9];
        bool   sa[9];
        #pragma unroll
        for (int k = 0; k < 9; ++k) {
            const int t = tid + k * 512;
            bool act = (t < PPB * 384);
            int p = 0, e = 0, ch = 0;
            if (act) {
                p = t / 384; const int lt = t - p * 384;
                e = lt >> 2; ch = lt & 3;
                act = (e < jcnt[p]);
            }
            sa[k] = act;
            if (act) {
                const int row = jlf[p * NN + e];
                sv[k] = *(const float4*)(edges +
                    ((size_t)b * NE + (size_t)(i0 + p) * NN + row) * FF + ch * 4);
            }
        }
        #pragma unroll
        for (int k = 0; k < 9; ++k)
            if (sa[k]) ebufq[tid + k * 512] = sv[k];
    }
    __syncthreads();                                  // C: ebuf + gmap ready

    // ---- compute: pure LDS+VALU group loop ----
    const float4* Wlq   = (const float4*)Wl;
    const float4* nodlq = (const float4*)nodl;
    const int Gtot = gtot_s;
    const int wq4  = 64 * tq + lane;                  // W float4 idx per f-row
    for (int fg = s; fg < Gtot; fg += 2) {
        const int p   = __builtin_amdgcn_readfirstlane(g2p[fg]);
        const int e0g = __builtin_amdgcn_readfirstlane(g2e0[fg]);
        const int cnt = __builtin_amdgcn_readfirstlane(jcnt[p]);
        const int ecnt = cnt - e0g;                   // >=1; epilogue caps at EG
        int jj[EG];
        #pragma unroll
        for (int e = 0; e < EG; ++e) {
            int idx = e0g + e; if (idx > cnt - 1) idx = cnt - 1;
            jj[e] = __builtin_amdgcn_readfirstlane(jlf[p * NN + idx]);
        }
        float acc[EG][4];
        #pragma unroll
        for (int e = 0; e < EG; ++e) {
            acc[e][0] = bvv.x; acc[e][1] = bvv.y;
            acc[e][2] = bvv.z; acc[e][3] = bvv.w;
        }
        const float4* fb = ebufq + p * 384 + e0g * 4; // uniform -> broadcast
        #pragma unroll
        for (int u = 0; u < 4; ++u) {
            float4 ev[EG];
            #pragma unroll
            for (int e = 0; e < EG; ++e) ev[e] = fb[e * 4 + u];
            #pragma unroll
            for (int f2 = 0; f2 < 4; ++f2) {
                const float4 w4 = Wlq[(4 * u + f2) * 256 + wq4];
                #pragma unroll
                for (int e = 0; e < EG; ++e) {
                    const float ef = (f2 == 0) ? ev[e].x : (f2 == 1) ? ev[e].y
                                   : (f2 == 2) ? ev[e].z : ev[e].w;
                    acc[e][0] = fmaf(ef, w4.x, acc[e][0]);
                    acc[e][1] = fmaf(ef, w4.y, acc[e][1]);
                    acc[e][2] = fmaf(ef, w4.z, acc[e][2]);
                    acc[e][3] = fmaf(ef, w4.w, acc[e][3]);
                }
            }
        }
        // epilogue: relu * nodes[j][q-chunk]; per-group partial in one reg
        float r = 0.f;
        #pragma unroll
        for (int e = 0; e < EG; ++e) {
            if (e < ecnt) {
                const float4 x4 = nodlq[jj[e] * 8 + l8];
                r = fmaf(fmaxf(acc[e][0], 0.f), x4.x, r);
                r = fmaf(fmaxf(acc[e][1], 0.f), x4.y, r);
                r = fmaf(fmaxf(acc[e][2], 0.f), x4.z, r);
                r = fmaf(fmaxf(acc[e][3], 0.f), x4.w, r);
            }
        }
        r += __shfl_xor(r, 1, 64);
        r += __shfl_xor(r, 2, 64);
        r += __shfl_xor(r, 4, 64);
        if (l8 == 0) atomicAdd(&aggv[p][8 * tq + lp], r);
    }
    __syncthreads();                                  // D: aggv final

    // ---- GRU phase: reuse Wl for w_ih/w_hh (padded stride 36) ----
    float* wihL = Wl;                // 96*36 floats
    float* whhL = Wl + 3456;
    for (int v = tid; v < 768; v += 512) {
        const int row = v >> 3, c4 = v & 7;
        *(float4*)&wihL[row * 36 + c4 * 4] = ((const float4*)w_ih)[v];
        *(float4*)&whhL[row * 36 + c4 * 4] = ((const float4*)w_hh)[v];
    }
    if (tid < 96) { bih_s[tid] = b_ih[tid]; bhh_s[tid] = b_hh[tid]; }
    __syncthreads();                                  // E: GRU weights ready

    if (tid < PPB * DD) {
        const int pp = tid >> 5, d = tid & 31;
        const float* x = nodl + (i0 + pp) * DD;
        // cell 1: h = 0 -> gh = b_hh exactly
        float gi_r = dot32(x, &wihL[(0 * 32 + d) * 36]) + bih_s[d];
        float gi_z = dot32(x, &wihL[(1 * 32 + d) * 36]) + bih_s[32 + d];
        float gi_n = dot32(x, &wihL[(2 * 32 + d) * 36]) + bih_s[64 + d];
        float r1 = sigm(gi_r + bhh_s[d]);
        float z1 = sigm(gi_z + bhh_s[32 + d]);
        float n1 = tanhf(gi_n + r1 * bhh_s[64 + d]);
        h1v[pp][d] = (1.f - z1) * n1;
    }
    __syncthreads();                                  // F: h1 ready
    if (tid < PPB * DD) {
        const int pp = tid >> 5, d = tid & 31;
        const float* a  = &aggv[pp][0];
        const float* h1 = &h1v[pp][0];
        float gi_r = dot32(a, &wihL[(0 * 32 + d) * 36]) + bih_s[d];
        float gi_z = dot32(a, &wihL[(1 * 32 + d) * 36]) + bih_s[32 + d];
        float gi_n = dot32(a, &wihL[(2 * 32 + d) * 36]) + bih_s[64 + d];
        float gh_r = dot32(h1, &whhL[(0 * 32 + d) * 36]) + bhh_s[d];
        float gh_z = dot32(h1, &whhL[(1 * 32 + d) * 36]) + bhh_s[32 + d];
        float gh_n = dot32(h1, &whhL[(2 * 32 + d) * 36]) + bhh_s[64 + d];
        float r2 = sigm(gi_r + gh_r);
        float z2 = sigm(gi_z + gh_z);
        float n2 = tanhf(gi_n + r2 * gh_n);
        float h2 = (1.f - z2) * n2 + z2 * h1[d];
        out[(size_t)(pair0 + pp) * DD + d] = h2;
    }
}

extern "C" void kernel_launch(void* const* d_in, const int* in_sizes, int n_in,
                              void* d_out, int out_size, void* d_ws, size_t ws_size,
                              hipStream_t stream) {
    const float* nodes = (const float*)d_in[0];
    const float* edges = (const float*)d_in[1];
    const float* mask  = (const float*)d_in[2];
    const float* W_agg = (const float*)d_in[3];
    const float* b_agg = (const float*)d_in[4];
    const float* w_ih  = (const float*)d_in[5];
    const float* w_hh  = (const float*)d_in[6];
    const float* b_ih  = (const float*)d_in[7];
    const float* b_hh  = (const float*)d_in[8];
    float* out = (float*)d_out;

    mp_fused<<<GRID_F, 512, 0, stream>>>(nodes, edges, mask, W_agg, b_agg,
                                         w_ih, w_hh, b_ih, b_hh, out);
}